// Round 1
// baseline (5055.503 us; speedup 1.0000x reference)
//
#include <hip/hip_runtime.h>
#include <hip/hip_bf16.h>
#include <math.h>

// Problem constants (fixed by reference)
#define B_ 2
#define S_ 2048
#define D_ 1024
#define M_ (B_*S_)      // 4096 rows
#define QKVLD 3072      // qkv row stride

// ---------------------------------------------------------------------------
// Generic fp32 GEMM: C[M,N] = A[M,K] @ W[N,K]^T + bias[N]
// Tiles: BM=BN=128, BK=16; 256 threads; 8x8 microtile per thread.
// M,N implied by grid (must be multiples of 128); K multiple of 16.
// ---------------------------------------------------------------------------
__global__ __launch_bounds__(256) void gemm_f32(
    const float* __restrict__ A, int lda,
    const float* __restrict__ W, int ldw,
    const float* __restrict__ bias,
    float* __restrict__ C, int ldc,
    int K)
{
    __shared__ __align__(16) float As[16][132];
    __shared__ __align__(16) float Ws[16][132];

    const int t  = threadIdx.x;
    const int bm = blockIdx.x * 128;
    const int bn = blockIdx.y * 128;
    const int ty = t >> 4;          // 0..15 -> rows ty*8..+7
    const int tx = t & 15;          // 0..15 -> cols tx*8..+7
    const int lr = t >> 2;          // 0..63
    const int lc = (t & 3) << 2;    // 0,4,8,12

    float acc[8][8];
    #pragma unroll
    for (int i = 0; i < 8; i++)
        #pragma unroll
        for (int j = 0; j < 8; j++) acc[i][j] = 0.f;

    for (int k0 = 0; k0 < K; k0 += 16) {
        #pragma unroll
        for (int half = 0; half < 2; half++) {
            int m = lr + half * 64;
            float4 a4 = *(const float4*)(A + (size_t)(bm + m) * lda + k0 + lc);
            As[lc+0][m] = a4.x; As[lc+1][m] = a4.y;
            As[lc+2][m] = a4.z; As[lc+3][m] = a4.w;
            float4 w4 = *(const float4*)(W + (size_t)(bn + m) * ldw + k0 + lc);
            Ws[lc+0][m] = w4.x; Ws[lc+1][m] = w4.y;
            Ws[lc+2][m] = w4.z; Ws[lc+3][m] = w4.w;
        }
        __syncthreads();
        #pragma unroll
        for (int k = 0; k < 16; k++) {
            float4 a0 = *(const float4*)&As[k][ty*8];
            float4 a1 = *(const float4*)&As[k][ty*8+4];
            float4 b0 = *(const float4*)&Ws[k][tx*8];
            float4 b1 = *(const float4*)&Ws[k][tx*8+4];
            float ar[8] = {a0.x,a0.y,a0.z,a0.w,a1.x,a1.y,a1.z,a1.w};
            float br[8] = {b0.x,b0.y,b0.z,b0.w,b1.x,b1.y,b1.z,b1.w};
            #pragma unroll
            for (int i = 0; i < 8; i++)
                #pragma unroll
                for (int j = 0; j < 8; j++)
                    acc[i][j] = fmaf(ar[i], br[j], acc[i][j]);
        }
        __syncthreads();
    }

    float bv[8];
    #pragma unroll
    for (int j = 0; j < 8; j++) bv[j] = bias[bn + tx*8 + j];
    #pragma unroll
    for (int i = 0; i < 8; i++) {
        float* cp = C + (size_t)(bm + ty*8 + i) * ldc + bn + tx*8;
        float4 o0 = {acc[i][0]+bv[0], acc[i][1]+bv[1], acc[i][2]+bv[2], acc[i][3]+bv[3]};
        float4 o1 = {acc[i][4]+bv[4], acc[i][5]+bv[5], acc[i][6]+bv[6], acc[i][7]+bv[7]};
        *(float4*)cp       = o0;
        *(float4*)(cp + 4) = o1;
    }
}

// ---------------------------------------------------------------------------
// Flash attention (no max-subtraction: scores bounded ~|s|<4, exp safe in fp32;
// softmax is shift-invariant so this matches the reference exactly in math).
// One block = (batch b, head h, 32 query rows). Loops 32-wide K/V tiles.
// Band mask: row i may attend j >= i - window (window<0 -> unmasked).
// Optionally stores per-row denominator l (for the long branch's prob pass).
// ---------------------------------------------------------------------------
template<int DK, int HEADS>
__global__ __launch_bounds__(256) void flash_attn(
    const float* __restrict__ qkv,   // [M_, 3072]: [q | k | v], head h at h*DK
    float* __restrict__ ctx,         // [M_, 1024]
    float* __restrict__ lout,        // [B_*HEADS*S_] or nullptr
    int window)
{
    constexpr int BQ = 32, BJ = 32;
    constexpr int LD = DK + 4;
    constexpr int OD = DK / 8;       // per-thread output floats
    __shared__ __align__(16) float Qs[BQ][LD];
    __shared__ __align__(16) float Ks[BJ][LD];
    __shared__ __align__(16) float Vs[BJ][LD];
    __shared__ __align__(16) float Ps[BQ][BJ + 4];
    __shared__ float Ls[BQ];

    const int t  = threadIdx.x;
    const int i0 = blockIdx.x * BQ;
    const int h  = blockIdx.y;
    const int b  = blockIdx.z;
    const float scale = rsqrtf((float)DK);

    const int qoff = h * DK;
    const int koff = D_ + h * DK;
    const int voff = 2 * D_ + h * DK;

    // Load+scale Q tile once
    #pragma unroll
    for (int e = t * 4; e < BQ * DK; e += 1024) {
        int r = e / DK, c = e % DK;
        float4 v = *(const float4*)(qkv + (size_t)(b*S_ + i0 + r) * QKVLD + qoff + c);
        v.x *= scale; v.y *= scale; v.z *= scale; v.w *= scale;
        *(float4*)&Qs[r][c] = v;
    }

    float O[OD];
    #pragma unroll
    for (int d = 0; d < OD; d++) O[d] = 0.f;
    float lp0 = 0.f, lp1 = 0.f;

    const int ty  = t >> 4;   // score rows 2ty, 2ty+1
    const int tx  = t & 15;   // score cols 2tx, 2tx+1
    const int pr  = t >> 3;   // PV row
    const int pdb = t & 7;    // PV d-block

    for (int j0 = 0; j0 < S_; j0 += BJ) {
        if (window >= 0 && (j0 + BJ - 1) < (i0 - window)) continue;  // fully masked tile
        __syncthreads();  // previous PV done before overwriting K/V
        #pragma unroll
        for (int e = t * 4; e < BJ * DK; e += 1024) {
            int r = e / DK, c = e % DK;
            size_t base = (size_t)(b*S_ + j0 + r) * QKVLD;
            *(float4*)&Ks[r][c] = *(const float4*)(qkv + base + koff + c);
            *(float4*)&Vs[r][c] = *(const float4*)(qkv + base + voff + c);
        }
        __syncthreads();

        // 2x2 scores
        float s00 = 0.f, s01 = 0.f, s10 = 0.f, s11 = 0.f;
        #pragma unroll
        for (int kk = 0; kk < DK; kk += 4) {
            float4 q0 = *(const float4*)&Qs[2*ty][kk];
            float4 q1 = *(const float4*)&Qs[2*ty+1][kk];
            float4 k0 = *(const float4*)&Ks[2*tx][kk];
            float4 k1 = *(const float4*)&Ks[2*tx+1][kk];
            s00 += q0.x*k0.x + q0.y*k0.y + q0.z*k0.z + q0.w*k0.w;
            s01 += q0.x*k1.x + q0.y*k1.y + q0.z*k1.z + q0.w*k1.w;
            s10 += q1.x*k0.x + q1.y*k0.y + q1.z*k0.z + q1.w*k0.w;
            s11 += q1.x*k1.x + q1.y*k1.y + q1.z*k1.z + q1.w*k1.w;
        }
        {
            int ig0 = i0 + 2*ty, ig1 = ig0 + 1;
            int jg0 = j0 + 2*tx, jg1 = jg0 + 1;
            bool msk = (window >= 0);
            float p00 = (msk && jg0 < ig0 - window) ? 0.f : __expf(s00);
            float p01 = (msk && jg1 < ig0 - window) ? 0.f : __expf(s01);
            float p10 = (msk && jg0 < ig1 - window) ? 0.f : __expf(s10);
            float p11 = (msk && jg1 < ig1 - window) ? 0.f : __expf(s11);
            Ps[2*ty  ][2*tx] = p00; Ps[2*ty  ][2*tx+1] = p01;
            Ps[2*ty+1][2*tx] = p10; Ps[2*ty+1][2*tx+1] = p11;
            lp0 += p00 + p01;
            lp1 += p10 + p11;
        }
        __syncthreads();

        // PV: O[pr][pdb*OD .. +OD) += P[pr][j] * V[j][..]
        #pragma unroll
        for (int j = 0; j < BJ; j++) {
            float pv = Ps[pr][j];
            #pragma unroll
            for (int dd = 0; dd < OD; dd += 4) {
                float4 v4 = *(const float4*)&Vs[j][pdb*OD + dd];
                O[dd+0] = fmaf(pv, v4.x, O[dd+0]);
                O[dd+1] = fmaf(pv, v4.y, O[dd+1]);
                O[dd+2] = fmaf(pv, v4.z, O[dd+2]);
                O[dd+3] = fmaf(pv, v4.w, O[dd+3]);
            }
        }
    }

    // Reduce l across the 16 tx lanes (tx = low 4 bits of lane id)
    #pragma unroll
    for (int m = 8; m >= 1; m >>= 1) {
        lp0 += __shfl_xor(lp0, m);
        lp1 += __shfl_xor(lp1, m);
    }
    if (tx == 0) { Ls[2*ty] = lp0; Ls[2*ty+1] = lp1; }
    __syncthreads();

    float linv = 1.f / Ls[pr];
    size_t crow = (size_t)(b*S_ + i0 + pr) * D_ + h*DK + pdb*OD;
    #pragma unroll
    for (int dd = 0; dd < OD; dd += 4) {
        float4 o4 = {O[dd]*linv, O[dd+1]*linv, O[dd+2]*linv, O[dd+3]*linv};
        *(float4*)(ctx + crow + dd) = o4;
    }
    if (lout != nullptr && t < BQ)
        lout[(size_t)(b*HEADS + h) * S_ + i0 + t] = Ls[t];
}

// ---------------------------------------------------------------------------
// Head-averaged long-branch attention probabilities:
//   attn[b,i,j] = (1/16) * sum_h exp(q_h.k_h/sqrt(64)) / l[b,h,i]
// One block owns a 32x64 (i,j) tile and loops all 16 heads -> single
// non-atomic coalesced write per element; no zero-init needed.
// ---------------------------------------------------------------------------
__global__ __launch_bounds__(256) void attn_mean(
    const float* __restrict__ qkv,   // long-branch qkv [M_,3072]
    const float* __restrict__ lbuf,  // [B_*16*S_]
    float* __restrict__ attn)        // [B_,S_,S_]
{
    constexpr int TI = 32, TJ = 64, DK = 64;
    __shared__ __align__(16) float Qs[TI][DK + 4];
    __shared__ __align__(16) float Ks[TJ][DK + 4];

    const int t  = threadIdx.x;
    const int j0 = blockIdx.x * TJ;
    const int i0 = blockIdx.y * TI;
    const int b  = blockIdx.z;
    const int ty = t >> 4;   // rows 2ty, 2ty+1
    const int tx = t & 15;   // cols 4tx..+3
    const float scale = 0.125f;  // 1/sqrt(64)

    float acc[2][4];
    #pragma unroll
    for (int ri = 0; ri < 2; ri++)
        #pragma unroll
        for (int cj = 0; cj < 4; cj++) acc[ri][cj] = 0.f;

    for (int h = 0; h < 16; h++) {
        __syncthreads();  // previous head's compute done
        {   // Q tile: 32x64, each thread 2 float4
            int r = t >> 3, c = (t & 7) * 8;
            const float* g = qkv + (size_t)(b*S_ + i0 + r) * QKVLD + h*DK + c;
            float4 v0 = *(const float4*)g;
            float4 v1 = *(const float4*)(g + 4);
            v0.x*=scale; v0.y*=scale; v0.z*=scale; v0.w*=scale;
            v1.x*=scale; v1.y*=scale; v1.z*=scale; v1.w*=scale;
            *(float4*)&Qs[r][c]   = v0;
            *(float4*)&Qs[r][c+4] = v1;
        }
        {   // K tile: 64x64, each thread 4 float4
            int r = t >> 2, c = (t & 3) * 16;
            const float* g = qkv + (size_t)(b*S_ + j0 + r) * QKVLD + D_ + h*DK + c;
            #pragma unroll
            for (int q4 = 0; q4 < 4; q4++)
                *(float4*)&Ks[r][c + q4*4] = *(const float4*)(g + q4*4);
        }
        __syncthreads();

        float linv0 = 1.f / lbuf[(size_t)(b*16 + h) * S_ + i0 + 2*ty];
        float linv1 = 1.f / lbuf[(size_t)(b*16 + h) * S_ + i0 + 2*ty + 1];

        float s[2][4];
        #pragma unroll
        for (int ri = 0; ri < 2; ri++)
            #pragma unroll
            for (int cj = 0; cj < 4; cj++) s[ri][cj] = 0.f;

        #pragma unroll
        for (int kk = 0; kk < DK; kk += 4) {
            float4 q0 = *(const float4*)&Qs[2*ty][kk];
            float4 q1 = *(const float4*)&Qs[2*ty+1][kk];
            #pragma unroll
            for (int cj = 0; cj < 4; cj++) {
                float4 k4 = *(const float4*)&Ks[4*tx + cj][kk];
                s[0][cj] += q0.x*k4.x + q0.y*k4.y + q0.z*k4.z + q0.w*k4.w;
                s[1][cj] += q1.x*k4.x + q1.y*k4.y + q1.z*k4.z + q1.w*k4.w;
            }
        }
        const float inv16 = 1.f / 16.f;
        #pragma unroll
        for (int cj = 0; cj < 4; cj++) {
            acc[0][cj] += __expf(s[0][cj]) * linv0 * inv16;
            acc[1][cj] += __expf(s[1][cj]) * linv1 * inv16;
        }
    }

    #pragma unroll
    for (int ri = 0; ri < 2; ri++) {
        float* p = attn + (size_t)(b*S_ + i0 + 2*ty + ri) * S_ + j0 + 4*tx;
        float4 o = {acc[ri][0], acc[ri][1], acc[ri][2], acc[ri][3]};
        *(float4*)p = o;
    }
}

// ---------------------------------------------------------------------------
// Residual + LayerNorm: out = LN(pre + x) * gamma + beta  (biased var, eps=1e-5)
// One 256-thread block per row; each thread one float4.
// ---------------------------------------------------------------------------
__global__ __launch_bounds__(256) void ln_residual(
    const float* __restrict__ pre, const float* __restrict__ x,
    const float* __restrict__ gamma, const float* __restrict__ beta,
    float* __restrict__ out)
{
    __shared__ float redS[4], redQ[4];
    const int row = blockIdx.x;
    const int t = threadIdx.x;
    size_t base = (size_t)row * D_ + t * 4;

    float4 v  = *(const float4*)(pre + base);
    float4 xv = *(const float4*)(x + base);
    v.x += xv.x; v.y += xv.y; v.z += xv.z; v.w += xv.w;

    float s = v.x + v.y + v.z + v.w;
    float q = v.x*v.x + v.y*v.y + v.z*v.z + v.w*v.w;
    #pragma unroll
    for (int m = 32; m >= 1; m >>= 1) {
        s += __shfl_xor(s, m);
        q += __shfl_xor(q, m);
    }
    int wave = t >> 6;
    if ((t & 63) == 0) { redS[wave] = s; redQ[wave] = q; }
    __syncthreads();
    s = redS[0] + redS[1] + redS[2] + redS[3];
    q = redQ[0] + redQ[1] + redQ[2] + redQ[3];

    float mean = s * (1.f / D_);
    float var  = q * (1.f / D_) - mean * mean;
    float rstd = rsqrtf(var + 1e-5f);

    float4 g  = *(const float4*)(gamma + t * 4);
    float4 be = *(const float4*)(beta + t * 4);
    float4 o;
    o.x = (v.x - mean) * rstd * g.x + be.x;
    o.y = (v.y - mean) * rstd * g.y + be.y;
    o.z = (v.z - mean) * rstd * g.z + be.z;
    o.w = (v.w - mean) * rstd * g.w + be.w;
    *(float4*)(out + base) = o;
}

// ---------------------------------------------------------------------------
extern "C" void kernel_launch(void* const* d_in, const int* in_sizes, int n_in,
                              void* d_out, int out_size, void* d_ws, size_t ws_size,
                              hipStream_t stream)
{
    (void)in_sizes; (void)n_in; (void)out_size; (void)ws_size;
    const float* x      = (const float*)d_in[0];
    const float* w_in_s = (const float*)d_in[1];
    const float* b_in_s = (const float*)d_in[2];
    const float* wo_s   = (const float*)d_in[3];
    const float* bo_s   = (const float*)d_in[4];
    const float* w_in_m = (const float*)d_in[5];
    const float* b_in_m = (const float*)d_in[6];
    const float* wo_m   = (const float*)d_in[7];
    const float* bo_m   = (const float*)d_in[8];
    const float* w_in_l = (const float*)d_in[9];
    const float* b_in_l = (const float*)d_in[10];
    const float* wo_l   = (const float*)d_in[11];
    const float* bo_l   = (const float*)d_in[12];
    const float* w_comb = (const float*)d_in[13];
    const float* b_comb = (const float*)d_in[14];
    const float* gamma  = (const float*)d_in[15];
    const float* beta   = (const float*)d_in[16];

    float* out    = (float*)d_out;                 // [B,S,D]
    float* attn_o = out + (size_t)M_ * D_;         // [B,S,S]

    // Workspace (floats): qkv 12.58M | ctx 4.19M | comb 12.58M | pre 4.19M | lbuf 64K
    float* ws   = (float*)d_ws;
    float* qkv  = ws;
    float* ctx  = ws + 12582912;
    float* comb = ws + 16777216;
    float* pre  = ws + 29360128;
    float* lbuf = ws + 33554432;   // total ~134.5 MB

    dim3 blk(256);
    dim3 g_qkv (M_/128, QKVLD/128);   // 32 x 24
    dim3 g_proj(M_/128, D_/128);      // 32 x 8
    dim3 g_fsm (S_/32, 8, B_);        // short/medium flash
    dim3 g_fl  (S_/32, 16, B_);       // long flash
    dim3 g_am  (S_/64, S_/32, B_);    // attn mean

    // short branch
    gemm_f32<<<g_qkv, blk, 0, stream>>>(x, D_, w_in_s, D_, b_in_s, qkv, QKVLD, D_);
    flash_attn<128, 8><<<g_fsm, blk, 0, stream>>>(qkv, ctx, nullptr, 10);
    gemm_f32<<<g_proj, blk, 0, stream>>>(ctx, D_, wo_s, D_, bo_s, comb + 0, QKVLD, D_);
    // medium branch
    gemm_f32<<<g_qkv, blk, 0, stream>>>(x, D_, w_in_m, D_, b_in_m, qkv, QKVLD, D_);
    flash_attn<128, 8><<<g_fsm, blk, 0, stream>>>(qkv, ctx, nullptr, 30);
    gemm_f32<<<g_proj, blk, 0, stream>>>(ctx, D_, wo_m, D_, bo_m, comb + 1024, QKVLD, D_);
    // long branch (stores per-row softmax denominators)
    gemm_f32<<<g_qkv, blk, 0, stream>>>(x, D_, w_in_l, D_, b_in_l, qkv, QKVLD, D_);
    flash_attn<64, 16><<<g_fl, blk, 0, stream>>>(qkv, ctx, lbuf, -1);
    gemm_f32<<<g_proj, blk, 0, stream>>>(ctx, D_, wo_l, D_, bo_l, comb + 2048, QKVLD, D_);
    attn_mean<<<g_am, blk, 0, stream>>>(qkv, lbuf, attn_o);
    // combine + residual LayerNorm
    gemm_f32<<<g_proj, blk, 0, stream>>>(comb, QKVLD, w_comb, QKVLD, b_comb, pre, D_, QKVLD);
    ln_residual<<<dim3(M_), blk, 0, stream>>>(pre, x, gamma, beta, out);
}

// Round 2
// 3216.139 us; speedup vs baseline: 1.5719x; 1.5719x over previous
//
#include <hip/hip_runtime.h>
#include <hip/hip_bf16.h>
#include <math.h>

// Problem constants (fixed by reference)
#define B_ 2
#define S_ 2048
#define D_ 1024
#define M_ (B_*S_)      // 4096 rows
#define QKVLD 3072      // qkv row stride

typedef _Float16 half8_t __attribute__((ext_vector_type(8)));
typedef _Float16 half4_t __attribute__((ext_vector_type(4)));
typedef float    f32x4  __attribute__((ext_vector_type(4)));

// async global->LDS, 16B per lane, wave-uniform LDS base + lane*16
#define GL2LDS(g, l) __builtin_amdgcn_global_load_lds( \
    (const __attribute__((address_space(1))) void*)(uintptr_t)(g), \
    (__attribute__((address_space(3))) void*)(l), 16, 0, 0)

// ---------------------------------------------------------------------------
// fp16-MFMA GEMM (m97 structure): C[M,N] = A[M,K] @ W[N,K]^T + bias
// 128x128 tile, BK=32, 256 thr = 4 waves, each wave 64x64 via 4x4 of 16x16x32.
// A,W are _Float16 row-major; accumulate fp32; OUT_HALF selects C dtype.
// ---------------------------------------------------------------------------
template<bool OUT_HALF>
__global__ __launch_bounds__(256) void gemm_f16(
    const _Float16* __restrict__ A, int lda,
    const _Float16* __restrict__ W, int ldw,
    const float* __restrict__ bias,
    void* __restrict__ C, int ldc, int K)
{
    __shared__ __align__(16) _Float16 As[128*32];
    __shared__ __align__(16) _Float16 Bs[128*32];

    const int t    = threadIdx.x;
    const int lane = t & 63;
    const int w    = t >> 6;
    const int bm   = blockIdx.x * 128;
    const int bn   = blockIdx.y * 128;
    const int wm   = (w >> 1) * 64;
    const int wn   = (w & 1) * 64;

    f32x4 acc[4][4] = {};

    // staging chunk geometry: chunk c covers LDS bytes [c*1024, (c+1)*1024)
    // global lane element: g = c*64+lane; row = g>>2; col8 = (g&3)*8
    const int c0 = w * 2;
    const int g0 = c0 * 64 + lane;
    const int g1 = g0 + 64;
    const int r0 = g0 >> 2, k80 = (g0 & 3) * 8;
    const int r1 = g1 >> 2, k81 = (g1 & 3) * 8;

    const _Float16* a0 = A + (size_t)(bm + r0) * lda + k80;
    const _Float16* a1 = A + (size_t)(bm + r1) * lda + k81;
    const _Float16* w0 = W + (size_t)(bn + r0) * ldw + k80;
    const _Float16* w1 = W + (size_t)(bn + r1) * ldw + k81;

    const int fr = lane & 15;          // fragment row/col within 16x16
    const int q8 = (lane >> 4) * 8;    // k offset of this lane's 8 elems

    for (int k0 = 0; k0 < K; k0 += 32) {
        __syncthreads();               // prev iter's ds_reads done
        GL2LDS(a0 + k0, As + c0*512);
        GL2LDS(a1 + k0, As + c0*512 + 512);
        GL2LDS(w0 + k0, Bs + c0*512);
        GL2LDS(w1 + k0, Bs + c0*512 + 512);
        __syncthreads();               // staging complete (barrier drains vmcnt)

        half8_t af[4], bf[4];
        #pragma unroll
        for (int mt = 0; mt < 4; mt++)
            af[mt] = *(const half8_t*)&As[(wm + mt*16 + fr)*32 + q8];
        #pragma unroll
        for (int nt = 0; nt < 4; nt++)
            bf[nt] = *(const half8_t*)&Bs[(wn + nt*16 + fr)*32 + q8];
        #pragma unroll
        for (int mt = 0; mt < 4; mt++)
            #pragma unroll
            for (int nt = 0; nt < 4; nt++)
                acc[mt][nt] = __builtin_amdgcn_mfma_f32_16x16x32_f16(
                    af[mt], bf[nt], acc[mt][nt], 0, 0, 0);
    }

    // C/D layout: col = lane&15, row = (lane>>4)*4 + reg
    const int cl = lane & 15;
    const int rq = (lane >> 4) * 4;
    #pragma unroll
    for (int mt = 0; mt < 4; mt++) {
        #pragma unroll
        for (int r = 0; r < 4; r++) {
            size_t grow = (size_t)(bm + wm + mt*16 + rq + r);
            #pragma unroll
            for (int nt = 0; nt < 4; nt++) {
                int gcol = bn + wn + nt*16 + cl;
                float v = acc[mt][nt][r] + bias[gcol];
                if constexpr (OUT_HALF)
                    ((_Float16*)C)[grow * ldc + gcol] = (_Float16)v;
                else
                    ((float*)C)[grow * ldc + gcol] = v;
            }
        }
    }
}

// ---------------------------------------------------------------------------
// float -> _Float16 cast, float4-vectorized
// ---------------------------------------------------------------------------
__global__ __launch_bounds__(256) void cast_f32_f16(
    const float* __restrict__ src, _Float16* __restrict__ dst, int n4)
{
    int i = blockIdx.x * 256 + threadIdx.x;
    if (i < n4) {
        float4 v = ((const float4*)src)[i];
        half4_t h = {(_Float16)v.x, (_Float16)v.y, (_Float16)v.z, (_Float16)v.w};
        ((half4_t*)dst)[i] = h;
    }
}

// ---------------------------------------------------------------------------
// Flash attention fp32 (no max-subtraction; scores bounded |s|<~4).
// Conflict-free LDS mappings:
//   scores cols tx, tx+16  -> K-row bank stride 4, 2 rows/bank = free
//   PV d-cols pdb*4 + 32*g -> V reads span all 32 banks in one phase
// Ps stride 33, Vs unpadded -> short/med LDS 54.5KB -> 3 blocks/CU.
// ctx written directly as _Float16 (feeds fp16 GEMM).
// ---------------------------------------------------------------------------
template<int DK, int HEADS>
__global__ __launch_bounds__(256) void flash_attn(
    const float* __restrict__ qkv,   // [M_, 3072]: [q | k | v]
    _Float16* __restrict__ ctx,      // [M_, 1024]
    float* __restrict__ lout,        // [B_*HEADS*S_] or nullptr
    int window)
{
    constexpr int BQ = 32, BJ = 32;
    constexpr int LD = DK + 4;
    constexpr int OD = DK / 8;       // per-thread output floats
    constexpr int NG = OD / 4;       // float4 groups per thread
    __shared__ __align__(16) float Qs[BQ][LD];
    __shared__ __align__(16) float Ks[BJ][LD];
    __shared__ __align__(16) float Vs[BJ][DK];
    __shared__ float Ps[BQ][33];
    __shared__ float Ls[BQ];

    const int t  = threadIdx.x;
    const int i0 = blockIdx.x * BQ;
    const int h  = blockIdx.y;
    const int b  = blockIdx.z;
    const float scale = rsqrtf((float)DK);

    const int qoff = h * DK;
    const int koff = D_ + h * DK;
    const int voff = 2 * D_ + h * DK;

    // Load+scale Q tile once
    #pragma unroll
    for (int e = t * 4; e < BQ * DK; e += 1024) {
        int r = e / DK, c = e % DK;
        float4 v = *(const float4*)(qkv + (size_t)(b*S_ + i0 + r) * QKVLD + qoff + c);
        v.x *= scale; v.y *= scale; v.z *= scale; v.w *= scale;
        *(float4*)&Qs[r][c] = v;
    }

    float O[OD];
    #pragma unroll
    for (int d = 0; d < OD; d++) O[d] = 0.f;
    float lp0 = 0.f, lp1 = 0.f;

    const int ty  = t >> 4;   // score rows 2ty, 2ty+1
    const int tx  = t & 15;   // score cols tx, tx+16
    const int pr  = t >> 3;   // PV row
    const int pdb = t & 7;    // PV d-block

    for (int j0 = 0; j0 < S_; j0 += BJ) {
        if (window >= 0 && (j0 + BJ - 1) < (i0 - window)) continue;  // fully masked tile
        __syncthreads();  // previous PV done before overwriting K/V
        #pragma unroll
        for (int e = t * 4; e < BJ * DK; e += 1024) {
            int r = e / DK, c = e % DK;
            size_t base = (size_t)(b*S_ + j0 + r) * QKVLD;
            *(float4*)&Ks[r][c] = *(const float4*)(qkv + base + koff + c);
            *(float4*)&Vs[r][c] = *(const float4*)(qkv + base + voff + c);
        }
        __syncthreads();

        // 2x2 scores: rows 2ty,2ty+1 x cols tx,tx+16
        float s00 = 0.f, s01 = 0.f, s10 = 0.f, s11 = 0.f;
        #pragma unroll
        for (int kk = 0; kk < DK; kk += 4) {
            float4 q0 = *(const float4*)&Qs[2*ty][kk];
            float4 q1 = *(const float4*)&Qs[2*ty+1][kk];
            float4 k0 = *(const float4*)&Ks[tx][kk];
            float4 k1 = *(const float4*)&Ks[tx+16][kk];
            s00 += q0.x*k0.x + q0.y*k0.y + q0.z*k0.z + q0.w*k0.w;
            s01 += q0.x*k1.x + q0.y*k1.y + q0.z*k1.z + q0.w*k1.w;
            s10 += q1.x*k0.x + q1.y*k0.y + q1.z*k0.z + q1.w*k0.w;
            s11 += q1.x*k1.x + q1.y*k1.y + q1.z*k1.z + q1.w*k1.w;
        }
        {
            int ig0 = i0 + 2*ty, ig1 = ig0 + 1;
            int jg0 = j0 + tx, jg1 = jg0 + 16;
            bool msk = (window >= 0);
            float p00 = (msk && jg0 < ig0 - window) ? 0.f : __expf(s00);
            float p01 = (msk && jg1 < ig0 - window) ? 0.f : __expf(s01);
            float p10 = (msk && jg0 < ig1 - window) ? 0.f : __expf(s10);
            float p11 = (msk && jg1 < ig1 - window) ? 0.f : __expf(s11);
            Ps[2*ty  ][tx] = p00; Ps[2*ty  ][tx+16] = p01;
            Ps[2*ty+1][tx] = p10; Ps[2*ty+1][tx+16] = p11;
            lp0 += p00 + p01;
            lp1 += p10 + p11;
        }
        __syncthreads();

        // PV: O accum at d = pdb*4 + 32*g
        #pragma unroll
        for (int j = 0; j < BJ; j++) {
            float pv = Ps[pr][j];
            #pragma unroll
            for (int g = 0; g < NG; g++) {
                float4 v4 = *(const float4*)&Vs[j][pdb*4 + 32*g];
                O[g*4+0] = fmaf(pv, v4.x, O[g*4+0]);
                O[g*4+1] = fmaf(pv, v4.y, O[g*4+1]);
                O[g*4+2] = fmaf(pv, v4.z, O[g*4+2]);
                O[g*4+3] = fmaf(pv, v4.w, O[g*4+3]);
            }
        }
    }

    // Reduce l across the 16 tx lanes
    #pragma unroll
    for (int m = 8; m >= 1; m >>= 1) {
        lp0 += __shfl_xor(lp0, m);
        lp1 += __shfl_xor(lp1, m);
    }
    if (tx == 0) { Ls[2*ty] = lp0; Ls[2*ty+1] = lp1; }
    __syncthreads();

    float linv = 1.f / Ls[pr];
    size_t crow = (size_t)(b*S_ + i0 + pr) * D_ + h*DK + pdb*4;
    #pragma unroll
    for (int g = 0; g < NG; g++) {
        half4_t o4 = {(_Float16)(O[g*4+0]*linv), (_Float16)(O[g*4+1]*linv),
                      (_Float16)(O[g*4+2]*linv), (_Float16)(O[g*4+3]*linv)};
        *(half4_t*)(ctx + crow + 32*g) = o4;
    }
    if (lout != nullptr && t < BQ)
        lout[(size_t)(b*HEADS + h) * S_ + i0 + t] = Ls[t];
}

// ---------------------------------------------------------------------------
// Head-averaged long-branch attention probabilities.
// Conflict-free col mapping: cols tx + 16*cj.
// ---------------------------------------------------------------------------
__global__ __launch_bounds__(256) void attn_mean(
    const float* __restrict__ qkv,   // long-branch qkv [M_,3072]
    const float* __restrict__ lbuf,  // [B_*16*S_]
    float* __restrict__ attn)        // [B_,S_,S_]
{
    constexpr int TI = 32, TJ = 64, DK = 64;
    __shared__ __align__(16) float Qs[TI][DK + 4];
    __shared__ __align__(16) float Ks[TJ][DK + 4];

    const int t  = threadIdx.x;
    const int j0 = blockIdx.x * TJ;
    const int i0 = blockIdx.y * TI;
    const int b  = blockIdx.z;
    const int ty = t >> 4;   // rows 2ty, 2ty+1
    const int tx = t & 15;   // cols tx + 16*cj
    const float scale = 0.125f;  // 1/sqrt(64)

    float acc[2][4];
    #pragma unroll
    for (int ri = 0; ri < 2; ri++)
        #pragma unroll
        for (int cj = 0; cj < 4; cj++) acc[ri][cj] = 0.f;

    for (int h = 0; h < 16; h++) {
        __syncthreads();  // previous head's compute done
        {   // Q tile: 32x64, each thread 2 float4
            int r = t >> 3, c = (t & 7) * 8;
            const float* g = qkv + (size_t)(b*S_ + i0 + r) * QKVLD + h*DK + c;
            float4 v0 = *(const float4*)g;
            float4 v1 = *(const float4*)(g + 4);
            v0.x*=scale; v0.y*=scale; v0.z*=scale; v0.w*=scale;
            v1.x*=scale; v1.y*=scale; v1.z*=scale; v1.w*=scale;
            *(float4*)&Qs[r][c]   = v0;
            *(float4*)&Qs[r][c+4] = v1;
        }
        {   // K tile: 64x64, each thread 4 float4
            int r = t >> 2, c = (t & 3) * 16;
            const float* g = qkv + (size_t)(b*S_ + j0 + r) * QKVLD + D_ + h*DK + c;
            #pragma unroll
            for (int q4 = 0; q4 < 4; q4++)
                *(float4*)&Ks[r][c + q4*4] = *(const float4*)(g + q4*4);
        }
        __syncthreads();

        float linv0 = 1.f / lbuf[(size_t)(b*16 + h) * S_ + i0 + 2*ty];
        float linv1 = 1.f / lbuf[(size_t)(b*16 + h) * S_ + i0 + 2*ty + 1];

        float s[2][4];
        #pragma unroll
        for (int ri = 0; ri < 2; ri++)
            #pragma unroll
            for (int cj = 0; cj < 4; cj++) s[ri][cj] = 0.f;

        #pragma unroll
        for (int kk = 0; kk < DK; kk += 4) {
            float4 q0 = *(const float4*)&Qs[2*ty][kk];
            float4 q1 = *(const float4*)&Qs[2*ty+1][kk];
            #pragma unroll
            for (int cj = 0; cj < 4; cj++) {
                float4 k4 = *(const float4*)&Ks[tx + 16*cj][kk];
                s[0][cj] += q0.x*k4.x + q0.y*k4.y + q0.z*k4.z + q0.w*k4.w;
                s[1][cj] += q1.x*k4.x + q1.y*k4.y + q1.z*k4.z + q1.w*k4.w;
            }
        }
        const float inv16 = 1.f / 16.f;
        #pragma unroll
        for (int cj = 0; cj < 4; cj++) {
            acc[0][cj] += __expf(s[0][cj]) * linv0 * inv16;
            acc[1][cj] += __expf(s[1][cj]) * linv1 * inv16;
        }
    }

    #pragma unroll
    for (int ri = 0; ri < 2; ri++) {
        float* p = attn + (size_t)(b*S_ + i0 + 2*ty + ri) * S_ + j0 + tx;
        #pragma unroll
        for (int cj = 0; cj < 4; cj++)
            p[16*cj] = acc[ri][cj];
    }
}

// ---------------------------------------------------------------------------
// Residual + LayerNorm
// ---------------------------------------------------------------------------
__global__ __launch_bounds__(256) void ln_residual(
    const float* __restrict__ pre, const float* __restrict__ x,
    const float* __restrict__ gamma, const float* __restrict__ beta,
    float* __restrict__ out)
{
    __shared__ float redS[4], redQ[4];
    const int row = blockIdx.x;
    const int t = threadIdx.x;
    size_t base = (size_t)row * D_ + t * 4;

    float4 v  = *(const float4*)(pre + base);
    float4 xv = *(const float4*)(x + base);
    v.x += xv.x; v.y += xv.y; v.z += xv.z; v.w += xv.w;

    float s = v.x + v.y + v.z + v.w;
    float q = v.x*v.x + v.y*v.y + v.z*v.z + v.w*v.w;
    #pragma unroll
    for (int m = 32; m >= 1; m >>= 1) {
        s += __shfl_xor(s, m);
        q += __shfl_xor(q, m);
    }
    int wave = t >> 6;
    if ((t & 63) == 0) { redS[wave] = s; redQ[wave] = q; }
    __syncthreads();
    s = redS[0] + redS[1] + redS[2] + redS[3];
    q = redQ[0] + redQ[1] + redQ[2] + redQ[3];

    float mean = s * (1.f / D_);
    float var  = q * (1.f / D_) - mean * mean;
    float rstd = rsqrtf(var + 1e-5f);

    float4 g  = *(const float4*)(gamma + t * 4);
    float4 be = *(const float4*)(beta + t * 4);
    float4 o;
    o.x = (v.x - mean) * rstd * g.x + be.x;
    o.y = (v.y - mean) * rstd * g.y + be.y;
    o.z = (v.z - mean) * rstd * g.z + be.z;
    o.w = (v.w - mean) * rstd * g.w + be.w;
    *(float4*)(out + base) = o;
}

// ---------------------------------------------------------------------------
extern "C" void kernel_launch(void* const* d_in, const int* in_sizes, int n_in,
                              void* d_out, int out_size, void* d_ws, size_t ws_size,
                              hipStream_t stream)
{
    (void)in_sizes; (void)n_in; (void)out_size; (void)ws_size;
    const float* x      = (const float*)d_in[0];
    const float* w_in_s = (const float*)d_in[1];
    const float* b_in_s = (const float*)d_in[2];
    const float* wo_s   = (const float*)d_in[3];
    const float* bo_s   = (const float*)d_in[4];
    const float* w_in_m = (const float*)d_in[5];
    const float* b_in_m = (const float*)d_in[6];
    const float* wo_m   = (const float*)d_in[7];
    const float* bo_m   = (const float*)d_in[8];
    const float* w_in_l = (const float*)d_in[9];
    const float* b_in_l = (const float*)d_in[10];
    const float* wo_l   = (const float*)d_in[11];
    const float* bo_l   = (const float*)d_in[12];
    const float* w_comb = (const float*)d_in[13];
    const float* b_comb = (const float*)d_in[14];
    const float* gamma  = (const float*)d_in[15];
    const float* beta   = (const float*)d_in[16];

    float* out    = (float*)d_out;                 // [B,S,D]
    float* attn_o = out + (size_t)M_ * D_;         // [B,S,S]

    // Workspace layout (float units):
    //   qkv      [0,          12582912)  fp32
    //   ctx_h    [12582912,   14680064)  4.19M halfs
    //   comb_h   [14680064,   20971520)  12.58M halfs
    //   lbuf     [20971520,   21037056)
    //   x_h      [21037056,   23134208)  4.19M halfs
    //   weights  [23134208,   30998528)  15.73M halfs
    //   pre aliases qkv[0, 4194304)  (qkv dead after attn_mean)
    float* ws   = (float*)d_ws;
    float*     qkv    = ws;
    _Float16*  ctx_h  = (_Float16*)(ws + 12582912);
    _Float16*  comb_h = (_Float16*)(ws + 14680064);
    float*     lbuf   = ws + 20971520;
    _Float16*  x_h    = (_Float16*)(ws + 21037056);
    _Float16*  wpool  = (_Float16*)(ws + 23134208);
    float*     pre    = ws;  // alias qkv

    _Float16* w_in_s_h = wpool;
    _Float16* w_in_m_h = wpool + 3145728;
    _Float16* w_in_l_h = wpool + 6291456;
    _Float16* wo_s_h   = wpool + 9437184;
    _Float16* wo_m_h   = wpool + 10485760;
    _Float16* wo_l_h   = wpool + 11534336;
    _Float16* w_comb_h = wpool + 12582912;

    dim3 blk(256);
    dim3 g_qkv (M_/128, QKVLD/128);   // 32 x 24
    dim3 g_proj(M_/128, D_/128);      // 32 x 8
    dim3 g_fsm (S_/32, 8, B_);
    dim3 g_fl  (S_/32, 16, B_);
    dim3 g_am  (S_/64, S_/32, B_);

    // ---- casts (fp32 -> fp16) ----
    cast_f32_f16<<<dim3(1048576/256), blk, 0, stream>>>(x, x_h, 1048576);
    cast_f32_f16<<<dim3(786432/256),  blk, 0, stream>>>(w_in_s, w_in_s_h, 786432);
    cast_f32_f16<<<dim3(786432/256),  blk, 0, stream>>>(w_in_m, w_in_m_h, 786432);
    cast_f32_f16<<<dim3(786432/256),  blk, 0, stream>>>(w_in_l, w_in_l_h, 786432);
    cast_f32_f16<<<dim3(262144/256),  blk, 0, stream>>>(wo_s, wo_s_h, 262144);
    cast_f32_f16<<<dim3(262144/256),  blk, 0, stream>>>(wo_m, wo_m_h, 262144);
    cast_f32_f16<<<dim3(262144/256),  blk, 0, stream>>>(wo_l, wo_l_h, 262144);
    cast_f32_f16<<<dim3(786432/256),  blk, 0, stream>>>(w_comb, w_comb_h, 786432);

    // ---- short branch ----
    gemm_f16<false><<<g_qkv, blk, 0, stream>>>(x_h, D_, w_in_s_h, D_, b_in_s, qkv, QKVLD, D_);
    flash_attn<128, 8><<<g_fsm, blk, 0, stream>>>(qkv, ctx_h, nullptr, 10);
    gemm_f16<true><<<g_proj, blk, 0, stream>>>(ctx_h, D_, wo_s_h, D_, bo_s, comb_h + 0, QKVLD, D_);
    // ---- medium branch ----
    gemm_f16<false><<<g_qkv, blk, 0, stream>>>(x_h, D_, w_in_m_h, D_, b_in_m, qkv, QKVLD, D_);
    flash_attn<128, 8><<<g_fsm, blk, 0, stream>>>(qkv, ctx_h, nullptr, 30);
    gemm_f16<true><<<g_proj, blk, 0, stream>>>(ctx_h, D_, wo_m_h, D_, bo_m, comb_h + 1024, QKVLD, D_);
    // ---- long branch ----
    gemm_f16<false><<<g_qkv, blk, 0, stream>>>(x_h, D_, w_in_l_h, D_, b_in_l, qkv, QKVLD, D_);
    flash_attn<64, 16><<<g_fl, blk, 0, stream>>>(qkv, ctx_h, lbuf, -1);
    gemm_f16<true><<<g_proj, blk, 0, stream>>>(ctx_h, D_, wo_l_h, D_, bo_l, comb_h + 2048, QKVLD, D_);
    attn_mean<<<g_am, blk, 0, stream>>>(qkv, lbuf, attn_o);
    // ---- combine + residual LayerNorm (pre aliases qkv; attn_mean already done) ----
    gemm_f16<false><<<g_proj, blk, 0, stream>>>(comb_h, QKVLD, w_comb_h, QKVLD, b_comb, pre, D_, QKVLD);
    ln_residual<<<dim3(M_), blk, 0, stream>>>(pre, x, gamma, beta, out);
}

// Round 3
// 854.764 us; speedup vs baseline: 5.9145x; 3.7626x over previous
//
#include <hip/hip_runtime.h>
#include <hip/hip_bf16.h>
#include <math.h>

// Problem constants (fixed by reference)
#define B_ 2
#define S_ 2048
#define D_ 1024
#define M_ (B_*S_)      // 4096 rows

typedef _Float16 half8_t __attribute__((ext_vector_type(8)));
typedef _Float16 half4_t __attribute__((ext_vector_type(4)));
typedef float    f32x4  __attribute__((ext_vector_type(4)));

// async global->LDS, 16B per lane, wave-uniform LDS base + lane*16
#define GL2LDS(g, l) __builtin_amdgcn_global_load_lds( \
    (const __attribute__((address_space(1))) void*)(uintptr_t)(g), \
    (__attribute__((address_space(3))) void*)(l), 16, 0, 0)

// ---------------------------------------------------------------------------
// fp16-MFMA GEMM: C[M,N] = A[M,K] @ W[N,K]^T + bias
// 128x128 tile, BK=32, 256 thr = 4 waves, each wave 64x64 via 4x4 of 16x16x32.
// MODE 0: C fp32, ldc. MODE 1: C fp16, ldc.
// MODE 2 (QKV split): cols <2048 -> fp16 C[row][col] (ldc=2048);
//                     cols>=2048 -> fp16 C2 = vT[col-2048][row] (transposed V).
// ---------------------------------------------------------------------------
template<int MODE>
__global__ __launch_bounds__(256) void gemm_f16(
    const _Float16* __restrict__ A, int lda,
    const _Float16* __restrict__ W, int ldw,
    const float* __restrict__ bias,
    void* __restrict__ C, int ldc, void* __restrict__ C2, int K)
{
    __shared__ __align__(16) _Float16 As[128*32];
    __shared__ __align__(16) _Float16 Bs[128*32];

    const int t    = threadIdx.x;
    const int lane = t & 63;
    const int w    = t >> 6;
    const int bm   = blockIdx.x * 128;
    const int bn   = blockIdx.y * 128;
    const int wm   = (w >> 1) * 64;
    const int wn   = (w & 1) * 64;

    f32x4 acc[4][4] = {};

    const int c0 = w * 2;
    const int g0 = c0 * 64 + lane;
    const int g1 = g0 + 64;
    const int r0 = g0 >> 2, k80 = (g0 & 3) * 8;
    const int r1 = g1 >> 2, k81 = (g1 & 3) * 8;

    const _Float16* a0 = A + (size_t)(bm + r0) * lda + k80;
    const _Float16* a1 = A + (size_t)(bm + r1) * lda + k81;
    const _Float16* w0 = W + (size_t)(bn + r0) * ldw + k80;
    const _Float16* w1 = W + (size_t)(bn + r1) * ldw + k81;

    const int fr = lane & 15;          // fragment row/col within 16x16
    const int q8 = (lane >> 4) * 8;    // k offset of this lane's 8 elems

    for (int k0 = 0; k0 < K; k0 += 32) {
        __syncthreads();
        GL2LDS(a0 + k0, As + c0*512);
        GL2LDS(a1 + k0, As + c0*512 + 512);
        GL2LDS(w0 + k0, Bs + c0*512);
        GL2LDS(w1 + k0, Bs + c0*512 + 512);
        __syncthreads();

        half8_t af[4], bf[4];
        #pragma unroll
        for (int mt = 0; mt < 4; mt++)
            af[mt] = *(const half8_t*)&As[(wm + mt*16 + fr)*32 + q8];
        #pragma unroll
        for (int nt = 0; nt < 4; nt++)
            bf[nt] = *(const half8_t*)&Bs[(wn + nt*16 + fr)*32 + q8];
        #pragma unroll
        for (int mt = 0; mt < 4; mt++)
            #pragma unroll
            for (int nt = 0; nt < 4; nt++)
                acc[mt][nt] = __builtin_amdgcn_mfma_f32_16x16x32_f16(
                    af[mt], bf[nt], acc[mt][nt], 0, 0, 0);
    }

    // C/D layout: col = lane&15, row = (lane>>4)*4 + reg
    const int cl = lane & 15;
    const int rq = (lane >> 4) * 4;

    if (MODE == 2 && bn >= 2048) {
        // V region -> transposed store, pack 4 contiguous rows as half4
        #pragma unroll
        for (int mt = 0; mt < 4; mt++) {
            int row0 = bm + wm + mt*16 + rq;
            #pragma unroll
            for (int nt = 0; nt < 4; nt++) {
                int gcol = bn + wn + nt*16 + cl;
                float bv = bias[gcol];
                half4_t hv = {(_Float16)(acc[mt][nt][0] + bv),
                              (_Float16)(acc[mt][nt][1] + bv),
                              (_Float16)(acc[mt][nt][2] + bv),
                              (_Float16)(acc[mt][nt][3] + bv)};
                *(half4_t*)((_Float16*)C2 + (size_t)(gcol - 2048) * M_ + row0) = hv;
            }
        }
        return;
    }

    #pragma unroll
    for (int mt = 0; mt < 4; mt++) {
        #pragma unroll
        for (int r = 0; r < 4; r++) {
            size_t grow = (size_t)(bm + wm + mt*16 + rq + r);
            #pragma unroll
            for (int nt = 0; nt < 4; nt++) {
                int gcol = bn + wn + nt*16 + cl;
                float v = acc[mt][nt][r] + bias[gcol];
                if (MODE == 0)
                    ((float*)C)[grow * ldc + gcol] = v;
                else
                    ((_Float16*)C)[grow * ldc + gcol] = (_Float16)v;
            }
        }
    }
}

// ---------------------------------------------------------------------------
// float -> _Float16 cast
// ---------------------------------------------------------------------------
__global__ __launch_bounds__(256) void cast_f32_f16(
    const float* __restrict__ src, _Float16* __restrict__ dst, int n4)
{
    int i = blockIdx.x * 256 + threadIdx.x;
    if (i < n4) {
        float4 v = ((const float4*)src)[i];
        half4_t h = {(_Float16)v.x, (_Float16)v.y, (_Float16)v.z, (_Float16)v.w};
        ((half4_t*)dst)[i] = h;
    }
}

// ---------------------------------------------------------------------------
// MFMA flash attention (no max-subtraction; |s*scale| < ~3, exp exact in f32).
// qk: [M_][2048] fp16 = [q | k]; vT: [H*DK][M_] fp16 (V transposed).
// Scores computed TRANSPOSED (S^T = K Q^T): C-layout then gives each lane 4
// j-contiguous P values at fixed q -> single ds_write_b64 into row-major-in-j
// Ps, which is exactly the PV A-fragment layout. PV = mfma(P, Vt).
// Band mask: q attends j >= q - window (window<0 = none).
// ---------------------------------------------------------------------------
template<int DK, int BQ, int H>
__global__ __launch_bounds__(256) void flash_mfma(
    const _Float16* __restrict__ qk,
    const _Float16* __restrict__ vT,
    _Float16* __restrict__ ctx,      // [M_][1024]
    float* __restrict__ lout,        // [B_*H*S_] or nullptr
    int window)
{
    constexpr int BJ  = 64;
    constexpr int LDK = DK + 8;     // halfs; 16B-multiple rows, uniform banks
    constexpr int LDP = BJ + 8;     // 72
    constexpr int NQT = BQ / 16;    // score col-tiles (q)
    constexpr int QW  = BQ / 4;     // q rows per wave in PV
    constexpr int MT  = QW / 16;    // PV m-tiles per wave
    constexpr int DT  = DK / 16;    // PV n-tiles (d)
    constexpr int KC  = BJ / 32;    // PV k-chunks
    constexpr int KS  = DK / 32;    // score k-chunks
    constexpr int CH  = DK / 8;     // half8 chunks per row

    __shared__ __align__(16) _Float16 Qs[BQ * LDK];
    __shared__ __align__(16) _Float16 Ks[BJ * LDK];
    __shared__ __align__(16) _Float16 Vt[DK * LDP];
    __shared__ __align__(16) _Float16 Ps[BQ * LDP];
    __shared__ float Lp[4][BQ];
    __shared__ float Lfin[BQ];

    const int t    = threadIdx.x;
    const int lane = t & 63, w = t >> 6;
    const int fr   = lane & 15, g = lane >> 4;
    const int q8   = g * 8;
    const int i0   = blockIdx.x * BQ;
    const int h    = blockIdx.y;
    const int b    = blockIdx.z;
    const float scale = (DK == 128) ? 0.08838834764831845f : 0.125f;

    // stage Q tile once
    for (int idx = t; idx < BQ * CH; idx += 256) {
        int r = idx / CH, c = idx % CH;
        *(half8_t*)&Qs[r*LDK + c*8] =
            *(const half8_t*)&qk[(size_t)(b*S_ + i0 + r)*2048 + h*DK + c*8];
    }

    f32x4 O[MT][DT] = {};
    float lsum[NQT] = {};

    for (int j0 = 0; j0 < S_; j0 += BJ) {
        if (window >= 0 && j0 + BJ - 1 < i0 - window) continue;  // fully masked
        __syncthreads();   // prev PV done before restaging
        for (int idx = t; idx < BJ * CH; idx += 256) {
            int r = idx / CH, c = idx % CH;
            *(half8_t*)&Ks[r*LDK + c*8] =
                *(const half8_t*)&qk[(size_t)(b*S_ + j0 + r)*2048 + 1024 + h*DK + c*8];
        }
        for (int idx = t; idx < DK * 8; idx += 256) {
            int d = idx >> 3, c = idx & 7;
            *(half8_t*)&Vt[d*LDP + c*8] =
                *(const half8_t*)&vT[(size_t)(h*DK + d)*M_ + b*S_ + j0 + c*8];
        }
        __syncthreads();   // staging visible

        const bool full = (window < 0) || (j0 >= i0 + BQ - 1 - window);
        // S^T: wave strip = 16 j-rows, loop q col-tiles
        #pragma unroll
        for (int ct = 0; ct < NQT; ct++) {
            f32x4 s = {};
            #pragma unroll
            for (int kk = 0; kk < KS; kk++) {
                half8_t af = *(const half8_t*)&Ks[(w*16 + fr)*LDK + kk*32 + q8];
                half8_t bf = *(const half8_t*)&Qs[(ct*16 + fr)*LDK + kk*32 + q8];
                s = __builtin_amdgcn_mfma_f32_16x16x32_f16(af, bf, s, 0, 0, 0);
            }
            // lane holds q = ct*16+fr (col), j = w*16 + g*4 + reg (rows)
            float p[4];
            #pragma unroll
            for (int r = 0; r < 4; r++) {
                float pv = __expf(s[r] * scale);
                if (!full) {
                    int jg = j0 + w*16 + g*4 + r;
                    int qg = i0 + ct*16 + fr;
                    if (jg < qg - window) pv = 0.f;
                }
                p[r] = pv;
                lsum[ct] += pv;
            }
            half4_t ph = {(_Float16)p[0], (_Float16)p[1],
                          (_Float16)p[2], (_Float16)p[3]};
            *(half4_t*)&Ps[(ct*16 + fr)*LDP + w*16 + g*4] = ph;
        }
        __syncthreads();   // Ps complete

        // PV: O[q-strip][d] += P[q][j] * V[j][d]  (B-frag from Vt)
        #pragma unroll
        for (int kc = 0; kc < KC; kc++) {
            half8_t pf[MT];
            #pragma unroll
            for (int mt = 0; mt < MT; mt++)
                pf[mt] = *(const half8_t*)&Ps[(w*QW + mt*16 + fr)*LDP + kc*32 + q8];
            #pragma unroll
            for (int dt = 0; dt < DT; dt++) {
                half8_t vf = *(const half8_t*)&Vt[(dt*16 + fr)*LDP + kc*32 + q8];
                #pragma unroll
                for (int mt = 0; mt < MT; mt++)
                    O[mt][dt] = __builtin_amdgcn_mfma_f32_16x16x32_f16(
                        pf[mt], vf, O[mt][dt], 0, 0, 0);
            }
        }
    }

    // row-sum reduction: over g groups (in-wave), then across waves via LDS
    #pragma unroll
    for (int ct = 0; ct < NQT; ct++) {
        lsum[ct] += __shfl_xor(lsum[ct], 16);
        lsum[ct] += __shfl_xor(lsum[ct], 32);
    }
    if (g == 0) {
        #pragma unroll
        for (int ct = 0; ct < NQT; ct++)
            Lp[w][ct*16 + fr] = lsum[ct];
    }
    __syncthreads();
    if (t < BQ) Lfin[t] = Lp[0][t] + Lp[1][t] + Lp[2][t] + Lp[3][t];
    __syncthreads();

    if (lout != nullptr && t < BQ)
        lout[(size_t)(b*H + h)*S_ + i0 + t] = Lfin[t];

    // epilogue: ctx = O / l  (fp16)
    #pragma unroll
    for (int mt = 0; mt < MT; mt++) {
        #pragma unroll
        for (int r = 0; r < 4; r++) {
            int ql = w*QW + mt*16 + g*4 + r;
            float linv = 1.f / Lfin[ql];
            _Float16* cp = ctx + (size_t)(b*S_ + i0 + ql)*D_ + h*DK;
            #pragma unroll
            for (int dt = 0; dt < DT; dt++)
                cp[dt*16 + fr] = (_Float16)(O[mt][dt][r] * linv);
        }
    }
}

// ---------------------------------------------------------------------------
// Head-averaged long-branch attention probabilities via MFMA:
//   attn[b,i,j] = (1/16) sum_h exp(q_h.k_h * 0.125) / l[b,h,i]
// 128x128 out tile per block, loops 16 heads.
// ---------------------------------------------------------------------------
__global__ __launch_bounds__(256) void attn_mean_mfma(
    const _Float16* __restrict__ qk,   // long-branch [M_][2048]
    const float* __restrict__ lbuf,    // [B_*16*S_]
    float* __restrict__ attn)          // [B_,S_,S_]
{
    constexpr int TI = 128, TJ = 128, LDK = 72;
    __shared__ __align__(16) _Float16 Qs[TI * LDK];
    __shared__ __align__(16) _Float16 Ks[TJ * LDK];
    __shared__ float Lh[TI];

    const int t = threadIdx.x, lane = t & 63, w = t >> 6;
    const int fr = lane & 15, g = lane >> 4, q8 = g * 8;
    const int j0 = blockIdx.x * TJ, i0 = blockIdx.y * TI, b = blockIdx.z;

    float acc[2][8][4] = {};

    for (int h = 0; h < 16; h++) {
        __syncthreads();
        for (int idx = t; idx < TI * 8; idx += 256) {
            int r = idx >> 3, c = idx & 7;
            *(half8_t*)&Qs[r*LDK + c*8] =
                *(const half8_t*)&qk[(size_t)(b*S_ + i0 + r)*2048 + h*64 + c*8];
            *(half8_t*)&Ks[r*LDK + c*8] =
                *(const half8_t*)&qk[(size_t)(b*S_ + j0 + r)*2048 + 1024 + h*64 + c*8];
        }
        if (t < TI) Lh[t] = lbuf[(size_t)(b*16 + h)*S_ + i0 + t];
        __syncthreads();

        half8_t af[2][2];
        #pragma unroll
        for (int mt = 0; mt < 2; mt++)
            #pragma unroll
            for (int kk = 0; kk < 2; kk++)
                af[mt][kk] = *(const half8_t*)&Qs[(w*32 + mt*16 + fr)*LDK + kk*32 + q8];

        #pragma unroll
        for (int nt = 0; nt < 8; nt++) {
            f32x4 s[2] = {};
            #pragma unroll
            for (int kk = 0; kk < 2; kk++) {
                half8_t bf = *(const half8_t*)&Ks[(nt*16 + fr)*LDK + kk*32 + q8];
                #pragma unroll
                for (int mt = 0; mt < 2; mt++)
                    s[mt] = __builtin_amdgcn_mfma_f32_16x16x32_f16(
                        af[mt][kk], bf, s[mt], 0, 0, 0);
            }
            #pragma unroll
            for (int mt = 0; mt < 2; mt++)
                #pragma unroll
                for (int r = 0; r < 4; r++) {
                    float linv = 1.f / Lh[w*32 + mt*16 + g*4 + r];
                    acc[mt][nt][r] += __expf(s[mt][r] * 0.125f) * linv;
                }
        }
    }

    #pragma unroll
    for (int mt = 0; mt < 2; mt++)
        #pragma unroll
        for (int r = 0; r < 4; r++) {
            size_t row = (size_t)(b*S_ + i0 + w*32 + mt*16 + g*4 + r)*S_ + j0;
            #pragma unroll
            for (int nt = 0; nt < 8; nt++)
                attn[row + nt*16 + fr] = acc[mt][nt][r] * 0.0625f;
        }
}

// ---------------------------------------------------------------------------
// Residual + LayerNorm
// ---------------------------------------------------------------------------
__global__ __launch_bounds__(256) void ln_residual(
    const float* __restrict__ pre, const float* __restrict__ x,
    const float* __restrict__ gamma, const float* __restrict__ beta,
    float* __restrict__ out)
{
    __shared__ float redS[4], redQ[4];
    const int row = blockIdx.x;
    const int t = threadIdx.x;
    size_t base = (size_t)row * D_ + t * 4;

    float4 v  = *(const float4*)(pre + base);
    float4 xv = *(const float4*)(x + base);
    v.x += xv.x; v.y += xv.y; v.z += xv.z; v.w += xv.w;

    float s = v.x + v.y + v.z + v.w;
    float q = v.x*v.x + v.y*v.y + v.z*v.z + v.w*v.w;
    #pragma unroll
    for (int m = 32; m >= 1; m >>= 1) {
        s += __shfl_xor(s, m);
        q += __shfl_xor(q, m);
    }
    int wave = t >> 6;
    if ((t & 63) == 0) { redS[wave] = s; redQ[wave] = q; }
    __syncthreads();
    s = redS[0] + redS[1] + redS[2] + redS[3];
    q = redQ[0] + redQ[1] + redQ[2] + redQ[3];

    float mean = s * (1.f / D_);
    float var  = q * (1.f / D_) - mean * mean;
    float rstd = rsqrtf(var + 1e-5f);

    float4 g  = *(const float4*)(gamma + t * 4);
    float4 be = *(const float4*)(beta + t * 4);
    float4 o;
    o.x = (v.x - mean) * rstd * g.x + be.x;
    o.y = (v.y - mean) * rstd * g.y + be.y;
    o.z = (v.z - mean) * rstd * g.z + be.z;
    o.w = (v.w - mean) * rstd * g.w + be.w;
    *(float4*)(out + base) = o;
}

// ---------------------------------------------------------------------------
extern "C" void kernel_launch(void* const* d_in, const int* in_sizes, int n_in,
                              void* d_out, int out_size, void* d_ws, size_t ws_size,
                              hipStream_t stream)
{
    (void)in_sizes; (void)n_in; (void)out_size; (void)ws_size;
    const float* x      = (const float*)d_in[0];
    const float* w_in_s = (const float*)d_in[1];
    const float* b_in_s = (const float*)d_in[2];
    const float* wo_s   = (const float*)d_in[3];
    const float* bo_s   = (const float*)d_in[4];
    const float* w_in_m = (const float*)d_in[5];
    const float* b_in_m = (const float*)d_in[6];
    const float* wo_m   = (const float*)d_in[7];
    const float* bo_m   = (const float*)d_in[8];
    const float* w_in_l = (const float*)d_in[9];
    const float* b_in_l = (const float*)d_in[10];
    const float* wo_l   = (const float*)d_in[11];
    const float* bo_l   = (const float*)d_in[12];
    const float* w_comb = (const float*)d_in[13];
    const float* b_comb = (const float*)d_in[14];
    const float* gamma  = (const float*)d_in[15];
    const float* beta   = (const float*)d_in[16];

    float* out    = (float*)d_out;                 // [B,S,D]
    float* attn_o = out + (size_t)M_ * D_;         // [B,S,S]

    // Workspace layout (byte offsets)
    char* W = (char*)d_ws;
    _Float16* qk     = (_Float16*)(W);               // [4096][2048] 16MB
    _Float16* vT     = (_Float16*)(W + 16777216);    // [1024][4096]  8MB
    _Float16* ctx_h  = (_Float16*)(W + 25165824);    // [4096][1024]  8MB
    _Float16* comb_h = (_Float16*)(W + 33554432);    // [4096][3072] 24MB
    float*    pre    = (float*)   (W + 58720256);    // [4096][1024] 16MB
    float*    lbuf   = (float*)   (W + 75497472);    // 256KB
    _Float16* x_h    = (_Float16*)(W + 75759616);    // 8MB
    _Float16* wpool  = (_Float16*)(W + 84148224);    // 30MB

    _Float16* w_in_s_h = wpool;
    _Float16* w_in_m_h = wpool + 3145728;
    _Float16* w_in_l_h = wpool + 6291456;
    _Float16* wo_s_h   = wpool + 9437184;
    _Float16* wo_m_h   = wpool + 10485760;
    _Float16* wo_l_h   = wpool + 11534336;
    _Float16* w_comb_h = wpool + 12582912;

    dim3 blk(256);
    dim3 g_qkv (M_/128, 3072/128);    // 32 x 24
    dim3 g_proj(M_/128, D_/128);      // 32 x 8
    dim3 g_fsm (S_/64, 8, B_);        // short/medium flash: BQ=64
    dim3 g_fl  (S_/128, 16, B_);      // long flash: BQ=128
    dim3 g_am  (S_/128, S_/128, B_);  // attn mean

    // ---- casts (fp32 -> fp16) ----
    cast_f32_f16<<<dim3(1048576/256), blk, 0, stream>>>(x, x_h, 1048576);
    cast_f32_f16<<<dim3(786432/256),  blk, 0, stream>>>(w_in_s, w_in_s_h, 786432);
    cast_f32_f16<<<dim3(786432/256),  blk, 0, stream>>>(w_in_m, w_in_m_h, 786432);
    cast_f32_f16<<<dim3(786432/256),  blk, 0, stream>>>(w_in_l, w_in_l_h, 786432);
    cast_f32_f16<<<dim3(262144/256),  blk, 0, stream>>>(wo_s, wo_s_h, 262144);
    cast_f32_f16<<<dim3(262144/256),  blk, 0, stream>>>(wo_m, wo_m_h, 262144);
    cast_f32_f16<<<dim3(262144/256),  blk, 0, stream>>>(wo_l, wo_l_h, 262144);
    cast_f32_f16<<<dim3(786432/256),  blk, 0, stream>>>(w_comb, w_comb_h, 786432);

    // ---- short branch ----
    gemm_f16<2><<<g_qkv, blk, 0, stream>>>(x_h, D_, w_in_s_h, D_, b_in_s, qk, 2048, vT, D_);
    flash_mfma<128, 64, 8><<<g_fsm, blk, 0, stream>>>(qk, vT, ctx_h, nullptr, 10);
    gemm_f16<1><<<g_proj, blk, 0, stream>>>(ctx_h, D_, wo_s_h, D_, bo_s, comb_h + 0, 3072, nullptr, D_);
    // ---- medium branch ----
    gemm_f16<2><<<g_qkv, blk, 0, stream>>>(x_h, D_, w_in_m_h, D_, b_in_m, qk, 2048, vT, D_);
    flash_mfma<128, 64, 8><<<g_fsm, blk, 0, stream>>>(qk, vT, ctx_h, nullptr, 30);
    gemm_f16<1><<<g_proj, blk, 0, stream>>>(ctx_h, D_, wo_m_h, D_, bo_m, comb_h + 1024, 3072, nullptr, D_);
    // ---- long branch ----
    gemm_f16<2><<<g_qkv, blk, 0, stream>>>(x_h, D_, w_in_l_h, D_, b_in_l, qk, 2048, vT, D_);
    flash_mfma<64, 128, 16><<<g_fl, blk, 0, stream>>>(qk, vT, ctx_h, lbuf, -1);
    gemm_f16<1><<<g_proj, blk, 0, stream>>>(ctx_h, D_, wo_l_h, D_, bo_l, comb_h + 2048, 3072, nullptr, D_);
    attn_mean_mfma<<<g_am, blk, 0, stream>>>(qk, lbuf, attn_o);
    // ---- combine + residual LayerNorm ----
    gemm_f16<0><<<g_proj, blk, 0, stream>>>(comb_h, 3072, w_comb_h, 3072, b_comb, pre, D_, nullptr, 3072);
    ln_residual<<<dim3(M_), blk, 0, stream>>>(pre, x, gamma, beta, out);
}